// Round 4
// baseline (188.856 us; speedup 1.0000x reference)
//
#include <hip/hip_runtime.h>
#include <hip/hip_bf16.h>

typedef __attribute__((ext_vector_type(8))) short short8;   // 8 bf16 (MFMA A/B frag)
typedef __attribute__((ext_vector_type(4))) float floatx4;  // MFMA C/D frag
typedef unsigned int u32;

#define D_DIM 256
#define TCOLS 32      // B-tile width -> dbuf LDS = 2*32*256*2 = 32768 B
#define TILES 8       // tiles per block -> 256 cols/block
#define IDX_BITS 0x1FFFu      // 13-bit index payload (N=M=8192)
#define VAL_MASK 0xFFFFE000u  // truncated value bits (sim+2 positive -> raw bits monotone)

// ---------- helpers ----------

__device__ inline unsigned short f2bf_rne(float f) {
  u32 u = __float_as_uint(f);
  u32 r = (u + 0x7FFFu + ((u >> 16) & 1u)) >> 16;
  return (unsigned short)r;
}

__device__ inline u32 umax(u32 a, u32 b) { return a > b ? a : b; }

__device__ inline void async_ld16(const void* g, void* l) {
  __builtin_amdgcn_global_load_lds((const __attribute__((address_space(1))) void*)g,
                                   (__attribute__((address_space(3))) void*)l, 16, 0, 0);
}

// ---------- kernels ----------

// Both [256][C] f32 -> [C][256] bf16 transposes in ONE launch (each extra
// dispatch costs ~10us wall in this harness). LDS-staged: coalesced 256B
// feature-row reads, coalesced short8 stores. Also folds best-array init.
__global__ __launch_bounds__(256) void transpose_cast2(const float* __restrict__ d0,
                                                       const float* __restrict__ d1,
                                                       unsigned short* __restrict__ At,
                                                       unsigned short* __restrict__ Bt,
                                                       int N, int M,
                                                       u32* __restrict__ best, int init_n) {
  __shared__ alignas(16) unsigned short tile[64 * 132];  // 16.9 KB
  const int tid = threadIdx.x;
  const int bx = blockIdx.x;
  const int nblkA = N / 64;
  const float* src;
  unsigned short* dst;
  int C, gd0;
  if (bx < nblkA) { src = d0; dst = At; C = N; gd0 = bx * 64; }
  else           { src = d1; dst = Bt; C = M; gd0 = (bx - nblkA) * 64; }
  const int d = tid & 63;
  const int fy = blockIdx.y;  // feature half: 0 or 1
#pragma unroll
  for (int k = 0; k < 32; ++k) {
    int fl = (tid >> 6) + 4 * k;  // 0..127 within the half
    float v = src[(size_t)(fy * 128 + fl) * C + gd0 + d];
    tile[d * 132 + fl] = f2bf_rne(v);
  }
  __syncthreads();
#pragma unroll
  for (int c = 0; c < 4; ++c) {
    int slot = c * 256 + tid;
    int dd = slot >> 4, f8 = slot & 15;
    short8 o = *(const short8*)(tile + dd * 132 + f8 * 8);
    *(short8*)(dst + (size_t)(gd0 + dd) * D_DIM + fy * 128 + f8 * 8) = o;
  }
  if (fy == 0) {
    int i = bx * 256 + tid;  // 256 blocks x 256 threads >= init_n
    if (i < init_n) best[i] = 0u;
  }
}

// Full-K-in-registers GEMM + fused argmax.
// R4 occupancy redesign: 32 rows/wave (was 64). Register ledger:
//   af[2][8]=64 VGPR + acc[2][2]=16 + rbk[8]=8 + temps ~30  => ~118 total,
//   under the 128-reg class boundary -> 4 waves/SIMD (R2's af[4][8]=128 made
//   2 waves/SIMD the hard ceiling; R1/R3 showed crossing a reg class in
//   either direction is a 2x cliff).
// Evidence for TLP-not-ILP: R3's counted-vmcnt/deferred-epilogue schedule
// left the per-wave tile latency unchanged (~7.5 kcy) -- the serial chain
// (ds_read -> MFMA -> epilogue VALU -> barrier drain) doesn't compress at
// source level; more independent waves per SIMD is what hides it. So:
// plain R2 dbuf + __syncthreads schedule (verified), 4 blocks/CU,
// 4-wave barrier groups from different blocks overlap each other's phases.
// LDS-read roofline for this shape: 16 waves/CU x 16KB B-frag reads per
// tile-period vs 2163cy matrix -> ~70% MfmaUtil ceiling (rows/wave is the
// only lever on B-bytes/MFMA; 64 rows costs the reg cliff -- not worth it).
// launch_bounds(256,4): cap = 128 regs, floor ~118 -> no spill (R1's
// disaster was floor >> cap; watch FETCH_SIZE to confirm).
// acc init = +2.0: outputs sim+2 in [1,3), positive -> raw IEEE bits
// monotone under unsigned compare -> no fmax/cndmask in the epilogue.
template <bool PRECAST>
__global__ __launch_bounds__(256, 4) void gemm_reduce(const float* __restrict__ A,
                                                      const unsigned short* __restrict__ At,
                                                      const unsigned short* __restrict__ Bt,
                                                      u32* __restrict__ best01,
                                                      u32* __restrict__ best10,
                                                      int N) {
  __shared__ alignas(16) unsigned short sB[2][TCOLS * D_DIM];  // 2 x 16 KB
  __shared__ u32 colbest[TILES * TCOLS];                       // 1 KB persistent col-best

  const int tid  = threadIdx.x;
  const int wave = tid >> 6;
  const int lane = tid & 63;
  const int quad = lane >> 4;
  const int l15  = lane & 15;
  const int n0   = blockIdx.x * 128;             // 128 rows/block
  const int mg0  = blockIdx.y * (TILES * TCOLS);
  const int rbase = n0 + wave * 32;              // 32 rows per wave

  colbest[tid] = 0u;  // TILES*TCOLS == 256 == blockDim

  // stage B tile 0 into buf 0 (LDS dest = uniform base + slot*16 — required)
  {
    const unsigned short* src = Bt + (size_t)mg0 * D_DIM;
#pragma unroll
    for (int c = 0; c < 4; ++c) {     // 1024 slots / 256 threads
      int slot = c * 256 + tid;
      int r = slot >> 5, cc = slot & 31;
      int ccg = (cc & 24) | ((cc ^ r) & 7);  // XOR-swizzle spreads frag-read banks
      async_ld16(src + (size_t)r * D_DIM + ccg * 8, (unsigned short*)sB[0] + slot * 8);
    }
  }

  // A fragments: wave's 32 rows x full K=256.
  short8 af[2][8];
  if constexpr (PRECAST) {
#pragma unroll
    for (int t = 0; t < 2; ++t) {
      const unsigned short* ap = At + (size_t)(rbase + t * 16 + l15) * D_DIM + quad * 8;
#pragma unroll
      for (int kc = 0; kc < 8; ++kc)
        af[t][kc] = *(const short8*)(ap + kc * 32);
    }
  } else {  // fallback: inline cast from f32 [256][N] (ws too small for At)
#pragma unroll
    for (int t = 0; t < 2; ++t)
#pragma unroll
      for (int kc = 0; kc < 8; ++kc) {
        const int row = rbase + t * 16 + l15;
        const int kb = kc * 32 + quad * 8;
        short8 o;
#pragma unroll
        for (int u = 0; u < 8; ++u)
          o[u] = (short)f2bf_rne(A[(size_t)(kb + u) * N + row]);
        af[t][kc] = o;
      }
  }

  u32 rbk[8];  // running row-argmax keys (8 rows per lane)
#pragma unroll
  for (int s = 0; s < 8; ++s) rbk[s] = 0u;
  const u32 rp0 = 0x1FFFu - (u32)(rbase + quad * 4);  // rowpay(i,r) = rp0 - 16i - r

  __syncthreads();  // drains vmcnt: B0 staged; colbest init visible

  for (int mt = 0; mt < TILES; ++mt) {
    const int m0 = mg0 + mt * TCOLS;
    if (mt + 1 < TILES) {  // prefetch next B tile — latency hides under MFMA
      const unsigned short* src = Bt + (size_t)(m0 + TCOLS) * D_DIM;
      unsigned short* dstb = (unsigned short*)sB[(mt + 1) & 1];
#pragma unroll
      for (int c = 0; c < 4; ++c) {
        int slot = c * 256 + tid;
        int r = slot >> 5, cc = slot & 31;
        int ccg = (cc & 24) | ((cc ^ r) & 7);
        async_ld16(src + (size_t)r * D_DIM + ccg * 8, dstb + slot * 8);
      }
    }

    floatx4 acc[2][2];
#pragma unroll
    for (int i = 0; i < 2; ++i)
#pragma unroll
      for (int j = 0; j < 2; ++j)
        acc[i][j] = (floatx4){2.0f, 2.0f, 2.0f, 2.0f};  // bias: outputs = sim+2 > 0

    const unsigned short* sb = (const unsigned short*)sB[mt & 1];
#pragma unroll
    for (int kc = 0; kc < 8; ++kc) {
      short8 bfr[2];
#pragma unroll
      for (int j = 0; j < 2; ++j) {
        int c2 = j * 16 + l15;
        int ch = kc * 4 + quad;
        int chg = (ch & 24) | ((ch ^ c2) & 7);  // un-swizzle
        bfr[j] = *(const short8*)(sb + c2 * D_DIM + chg * 8);
      }
#pragma unroll
      for (int i = 0; i < 2; ++i)
#pragma unroll
        for (int j = 0; j < 2; ++j)
          acc[i][j] = __builtin_amdgcn_mfma_f32_16x16x32_bf16(af[i][kc], bfr[j], acc[i][j], 0, 0, 0);
    }

    // ---- epilogue. C/D map: col = j*16 + l15, row = i*16 + quad*4 + r
    u32 cb[2] = {0u, 0u};
    u32 colpay[2] = {0x1FFFu - (u32)(m0 + l15), 0x1FFFu - (u32)(m0 + 16 + l15)};
#pragma unroll
    for (int i = 0; i < 2; ++i)
#pragma unroll
      for (int r = 0; r < 4; ++r) {
        u32 rp = rp0 - (u32)(i * 16 + r);  // row payload (no array: reg save)
        u32 rb = rbk[i * 4 + r];
#pragma unroll
        for (int j = 0; j < 2; ++j) {
          u32 u = __float_as_uint(acc[i][j][r]) & VAL_MASK;  // positive -> monotone
          rb = umax(rb, u | colpay[j]);
          cb[j] = umax(cb[j], u | rp);
        }
        rbk[i * 4 + r] = rb;
      }
    // col-argmax: butterfly over the 4 quads, then LDS atomic (NOT global —
    // keeps the global-atomic latency off the per-tile barrier drain)
#pragma unroll
    for (int j = 0; j < 2; ++j) {
      u32 b = cb[j];
      b = umax(b, (u32)__shfl_xor((int)b, 16, 64));
      b = umax(b, (u32)__shfl_xor((int)b, 32, 64));
      if (quad == 0) atomicMax(&colbest[mt * TCOLS + j * 16 + l15], b);
    }
    __syncthreads();  // ds_reads of sb done; vmcnt drained -> next B ready
  }

  // ---- final row reduction: butterfly over l15, one atomic per row
#pragma unroll
  for (int i = 0; i < 2; ++i)
#pragma unroll
    for (int r = 0; r < 4; ++r) {
      u32 b = rbk[i * 4 + r];
      b = umax(b, (u32)__shfl_xor((int)b, 1, 64));
      b = umax(b, (u32)__shfl_xor((int)b, 2, 64));
      b = umax(b, (u32)__shfl_xor((int)b, 4, 64));
      b = umax(b, (u32)__shfl_xor((int)b, 8, 64));
      if (l15 == 0) atomicMax(&best01[rbase + i * 16 + quad * 4 + r], b);
    }

  // ---- col flush: colbest complete as of the last tile-loop barrier
  atomicMax(&best10[mg0 + tid], colbest[tid]);
}

__global__ void finalize(const u32* __restrict__ best01, const u32* __restrict__ best10,
                         float* __restrict__ out, int N) {
  int n = blockIdx.x * blockDim.x + threadIdx.x;
  if (n >= N) return;
  u32 k = best01[n];
  int idx01 = (int)((~k) & IDX_BITS);
  float sim = __uint_as_float(k & VAL_MASK) - 2.0f;  // undo +2 bias
  int idx10 = (int)((~best10[idx01]) & IDX_BITS);
  float dist = 2.0f - 2.0f * sim;             // squared L2 for unit vectors
  bool ok = (idx10 == n) && (dist <= 0.64f);  // mutual NN + thresh^2
  out[n]     = ok ? (float)idx01 : -1.0f;
  out[N + n] = ok ? 1.5f - sim : 0.0f;        // (dist+1)/2
}

// ---------- launcher ----------

extern "C" void kernel_launch(void* const* d_in, const int* in_sizes, int n_in,
                              void* d_out, int out_size, void* d_ws, size_t ws_size,
                              hipStream_t stream) {
  (void)n_in; (void)out_size;
  const float* d0 = (const float*)d_in[0];  // [256][N]
  const float* d1 = (const float*)d_in[1];  // [256][M]
  const int N = in_sizes[0] / D_DIM;        // 8192
  const int M = in_sizes[1] / D_DIM;        // 8192

  u32* best01 = (u32*)d_ws;                          // N u32
  u32* best10 = best01 + N;                          // M u32
  unsigned short* At = (unsigned short*)(best10 + M);  // [N][256] bf16
  unsigned short* Bt = At + (size_t)N * D_DIM;         // [M][256] bf16
  float* out = (float*)d_out;

  const size_t need = (size_t)(N + M) * sizeof(u32) +
                      (size_t)(N + M) * D_DIM * sizeof(unsigned short);

  if (ws_size >= need) {
    hipLaunchKernelGGL(transpose_cast2, dim3((N + M) / 64, 2), dim3(256), 0, stream,
                       d0, d1, At, Bt, N, M, best01, N + M);
    hipLaunchKernelGGL((gemm_reduce<true>), dim3(N / 128, M / (TILES * TCOLS)), dim3(256),
                       0, stream, d0, At, Bt, best01, best10, N);
  } else {
    // ws too small for At: B-only precast, inline A cast
    unsigned short* BtF = (unsigned short*)(best10 + M);
    hipLaunchKernelGGL(transpose_cast2, dim3(M / 64, 2), dim3(256), 0, stream,
                       d1, d1, BtF, BtF, M, M, best01, N + M);
    hipLaunchKernelGGL((gemm_reduce<false>), dim3(N / 128, M / (TILES * TCOLS)), dim3(256),
                       0, stream, d0, BtF, BtF, best01, best10, N);
  }
  hipLaunchKernelGGL(finalize, dim3(N / 256), dim3(256), 0, stream, best01, best10, out, N);
}

// Round 5
// 114.267 us; speedup vs baseline: 1.6528x; 1.6528x over previous
//
#include <hip/hip_runtime.h>
#include <hip/hip_bf16.h>

typedef __attribute__((ext_vector_type(8))) short short8;   // 8 bf16 (MFMA A/B frag)
typedef __attribute__((ext_vector_type(4))) float floatx4;  // MFMA C/D frag
typedef unsigned int u32;

#define D_DIM 256
#define TCOLS 32      // tile width (cols per epilogue chunk)
#define TILES 8       // tiles per block -> 256 cols/block
#define IDX_BITS 0x1FFFu      // 13-bit index payload (N=M=8192)
#define VAL_MASK 0xFFFFE000u  // truncated value bits (sim+2 positive -> raw bits monotone)

// ---------- helpers ----------

__device__ inline unsigned short f2bf_rne(float f) {
  u32 u = __float_as_uint(f);
  u32 r = (u + 0x7FFFu + ((u >> 16) & 1u)) >> 16;
  return (unsigned short)r;
}

__device__ inline u32 umax(u32 a, u32 b) { return a > b ? a : b; }

// ---------- kernels ----------

// One launch, both inputs. A -> row-major At[row][256] bf16.
// B -> FRAGMENT-ORDERED Bt2: for col-group g (32 cols), the b128 payload of
// MFMA B-frag (kc, j, lane) lives at u16 offset
//     g*8192 + (kc*2 + j)*512 + lane*8          (lane = quad*16 + l15)
// so each GEMM B-frag load is one contiguous 1KB/wave global read from L2 —
// this is what lets the GEMM skip LDS staging entirely.
// Element map: col c (=j*16+l15 within group), feat f (kc=f>>5, q=(f>>3)&3):
//     off = (c>>5 grp)*8192 + (f>>5)*1024 + ((c>>4)&1)*512 + ((f>>3)&3)*128
//           + (c&15)*8 + (f&7)
__global__ __launch_bounds__(256) void transpose_cast2(const float* __restrict__ d0,
                                                       const float* __restrict__ d1,
                                                       unsigned short* __restrict__ At,
                                                       unsigned short* __restrict__ Bt2,
                                                       int N, int M,
                                                       u32* __restrict__ best, int init_n) {
  __shared__ alignas(16) unsigned short tile[64 * 132];  // 16.9 KB, pad->2-way reads
  const int tid = threadIdx.x;
  const int bx = blockIdx.x;
  const int nblkA = N / 64;       // pass N=0 to do B only (fallback path)
  const bool isA = bx < nblkA;
  const float* src = isA ? d0 : d1;
  const int C = isA ? N : M;
  const int gd0 = (isA ? bx : bx - nblkA) * 64;
  const int d = tid & 63;
  const int fy = blockIdx.y;  // feature half: 0 or 1
#pragma unroll
  for (int k = 0; k < 32; ++k) {
    int fl = (tid >> 6) + 4 * k;  // 0..127 within the half
    float v = src[(size_t)(fy * 128 + fl) * C + gd0 + d];
    tile[d * 132 + fl] = f2bf_rne(v);
  }
  __syncthreads();
  if (isA) {
#pragma unroll
    for (int c = 0; c < 4; ++c) {
      int slot = c * 256 + tid;
      int dd = slot >> 4, f8 = slot & 15;
      short8 o = *(const short8*)(tile + dd * 132 + f8 * 8);
      *(short8*)(At + (size_t)(gd0 + dd) * D_DIM + fy * 128 + f8 * 8) = o;
    }
  } else {
#pragma unroll
    for (int c = 0; c < 4; ++c) {
      int slot = c * 256 + tid;
      int dd = slot & 63;            // col within block
      int f8l = c * 4 + (tid >> 6);  // 8-feat chunk within half, 0..15
      int f8g = fy * 16 + f8l;       // global 8-feat chunk = (kc,q): one b128 payload
      short8 o = *(const short8*)(tile + dd * 132 + f8l * 8);
      size_t off = (size_t)((gd0 + dd) >> 5) * 8192 + (size_t)(f8g >> 2) * 1024 +
                   (size_t)((dd >> 4) & 1) * 512 + (f8g & 3) * 128 + (dd & 15) * 8;
      *(short8*)(Bt2 + off) = o;
    }
  }
  if (fy == 0) {
    int i = bx * 256 + tid;
    if (i < init_n) best[i] = 0u;
  }
}

// Full-K-in-registers GEMM + fused argmax — NO LDS STAGING, NO MAIN-LOOP
// BARRIERS. B-frags read straight from L2 via fragment-ordered Bt2 (1KB/wave
// contiguous per load). Rationale (R2 counters): with LDS staging every wave
// read the full 16KB tile from LDS anyway (no per-wave saving), the LDS pipe
// ran at ~100% (2.1M bank-conflict cycles), and the per-tile __syncthreads
// vmcnt(0) drain phase-locked the 4 waves -> MfmaUtil stuck at 24.5%. Bt is
// 4MB = L2-resident; free-running waves hide latency instead.
// Register ledger (R1/R3/R4 lessons: ledger must stay << 256 and NEVER cap
// below the natural floor): af 128 + bfA 32 + acc 32 + rbk 16 + temps ~25
// = ~233 -> launch_bounds(256,2) cap 256, margin ~23. Single bfA bank: the
// kc4..7 load latency (~300cy L2) is the price for staying off the 256
// cliff; the co-resident wave's MFMAs cover the pipe during the wait.
// XCD swizzle: bid -> (x, y) with all blocks of a y-stripe on one XCD
// (XCD = bid%8 round-robin dispatch): per-XCD B working set = 4 stripes x
// 128KB = 512KB << 4MB L2.
// acc init = +2.0: outputs sim+2 in [1,3) -> raw bits monotone unsigned.
template <bool PRECAST>
__global__ __launch_bounds__(256, 2) void gemm_reduce(const float* __restrict__ A,
                                                      const unsigned short* __restrict__ At,
                                                      const unsigned short* __restrict__ Bt2,
                                                      u32* __restrict__ best01,
                                                      u32* __restrict__ best10,
                                                      int N, int M) {
  __shared__ u32 colbest[TILES * TCOLS];  // 1 KB — the only LDS

  const int tid  = threadIdx.x;
  const int wave = tid >> 6;
  const int lane = tid & 63;
  const int quad = lane >> 4;
  const int l15  = lane & 15;

  // XCD-chunked decode: y-stripe constant per XCD (bijective when yB%8==0)
  const int xB = N >> 8, yB = M >> 8;
  const int bid = blockIdx.x;
  int x, y;
  if ((yB & 7) == 0) {
    int c = bid & 7, k = bid >> 3;
    x = k % xB;
    y = c * (yB >> 3) + k / xB;
  } else {
    x = bid % xB;
    y = bid / xB;
  }
  const int n0  = x * 256;
  const int mg0 = y * (TILES * TCOLS);
  const int rbase = n0 + wave * 64;  // 64 rows per wave

  colbest[tid] = 0u;  // TILES*TCOLS == 256 == blockDim

  // A fragments: wave's 64 rows x full K=256.
  short8 af[4][8];
  if constexpr (PRECAST) {
#pragma unroll
    for (int t = 0; t < 4; ++t) {
      const unsigned short* ap = At + (size_t)(rbase + t * 16 + l15) * D_DIM + quad * 8;
#pragma unroll
      for (int kc = 0; kc < 8; ++kc)
        af[t][kc] = *(const short8*)(ap + kc * 32);
    }
  } else {  // fallback: inline cast from f32 [256][N]
#pragma unroll
    for (int t = 0; t < 4; ++t)
#pragma unroll
      for (int kc = 0; kc < 8; ++kc) {
        const int row = rbase + t * 16 + l15;
        const int kb = kc * 32 + quad * 8;
        short8 o;
#pragma unroll
        for (int u = 0; u < 8; ++u)
          o[u] = (short)f2bf_rne(A[(size_t)(kb + u) * N + row]);
        af[t][kc] = o;
      }
  }

  // B-frag base: per-lane address inside fragment-ordered Bt2
  const unsigned short* bp = Bt2 + (size_t)(mg0 >> 5) * 8192 + (size_t)lane * 8;

  // prologue: tile 0, kc 0..3
  short8 bfA[4][2];
#pragma unroll
  for (int kc = 0; kc < 4; ++kc)
#pragma unroll
    for (int j = 0; j < 2; ++j)
      bfA[kc][j] = *(const short8*)(bp + (kc * 2 + j) * 512);

  u32 rbk[16];
#pragma unroll
  for (int s = 0; s < 16; ++s) rbk[s] = 0u;
  const u32 rp0 = 0x1FFFu - (u32)(rbase + quad * 4);  // rowpay(i,r) = rp0 - 16i - r

  __syncthreads();  // colbest init visible (only barrier before the end)

  for (int mt = 0; mt < TILES; ++mt) {
    const unsigned short* bpt = bp + (size_t)mt * 8192;
    floatx4 acc[4][2];
#pragma unroll
    for (int i = 0; i < 4; ++i)
#pragma unroll
      for (int j = 0; j < 2; ++j)
        acc[i][j] = (floatx4){2.0f, 2.0f, 2.0f, 2.0f};  // bias: outputs = sim+2 > 0

    // MFMA kc0..3 from resident bfA
#pragma unroll
    for (int kc = 0; kc < 4; ++kc)
#pragma unroll
      for (int i = 0; i < 4; ++i)
#pragma unroll
        for (int j = 0; j < 2; ++j)
          acc[i][j] = __builtin_amdgcn_mfma_f32_16x16x32_bf16(af[i][kc], bfA[kc][j], acc[i][j], 0, 0, 0);

    // reload bfA <- this tile's kc4..7 (WAR: issues right after MFMAs above)
#pragma unroll
    for (int kc = 0; kc < 4; ++kc)
#pragma unroll
      for (int j = 0; j < 2; ++j)
        bfA[kc][j] = *(const short8*)(bpt + ((kc + 4) * 2 + j) * 512);

    // MFMA kc4..7 (waits counted vmcnt; co-resident wave fills the pipe)
#pragma unroll
    for (int kc = 0; kc < 4; ++kc)
#pragma unroll
      for (int i = 0; i < 4; ++i)
#pragma unroll
        for (int j = 0; j < 2; ++j)
          acc[i][j] = __builtin_amdgcn_mfma_f32_16x16x32_bf16(af[i][kc + 4], bfA[kc][j], acc[i][j], 0, 0, 0);

    // reload bfA <- next tile kc0..3; latency covered by the epilogue below
    if (mt + 1 < TILES) {
#pragma unroll
      for (int kc = 0; kc < 4; ++kc)
#pragma unroll
        for (int j = 0; j < 2; ++j)
          bfA[kc][j] = *(const short8*)(bpt + 8192 + (kc * 2 + j) * 512);
    }

    // ---- epilogue. C/D map: col = j*16 + l15, row = i*16 + quad*4 + r
    const int m0 = mg0 + mt * TCOLS;
    u32 cb[2] = {0u, 0u};
    u32 colpay[2] = {0x1FFFu - (u32)(m0 + l15), 0x1FFFu - (u32)(m0 + 16 + l15)};
#pragma unroll
    for (int i = 0; i < 4; ++i)
#pragma unroll
      for (int r = 0; r < 4; ++r) {
        u32 rp = rp0 - (u32)(i * 16 + r);
        u32 rb = rbk[i * 4 + r];
#pragma unroll
        for (int j = 0; j < 2; ++j) {
          u32 u = __float_as_uint(acc[i][j][r]) & VAL_MASK;  // positive -> monotone
          rb = umax(rb, u | colpay[j]);
          cb[j] = umax(cb[j], u | rp);
        }
        rbk[i * 4 + r] = rb;
      }
    // col-argmax: butterfly over the 4 quads, then LDS atomic (no barrier)
#pragma unroll
    for (int j = 0; j < 2; ++j) {
      u32 b = cb[j];
      b = umax(b, (u32)__shfl_xor((int)b, 16, 64));
      b = umax(b, (u32)__shfl_xor((int)b, 32, 64));
      if (quad == 0) atomicMax(&colbest[mt * TCOLS + j * 16 + l15], b);
    }
  }

  // ---- final row reduction: butterfly over l15, one atomic per row
#pragma unroll
  for (int i = 0; i < 4; ++i)
#pragma unroll
    for (int r = 0; r < 4; ++r) {
      u32 b = rbk[i * 4 + r];
      b = umax(b, (u32)__shfl_xor((int)b, 1, 64));
      b = umax(b, (u32)__shfl_xor((int)b, 2, 64));
      b = umax(b, (u32)__shfl_xor((int)b, 4, 64));
      b = umax(b, (u32)__shfl_xor((int)b, 8, 64));
      if (l15 == 0) atomicMax(&best01[rbase + i * 16 + quad * 4 + r], b);
    }

  // ---- col flush: wait all waves' colbest LDS atomics, then one global each
  __syncthreads();
  atomicMax(&best10[mg0 + tid], colbest[tid]);
}

__global__ void finalize(const u32* __restrict__ best01, const u32* __restrict__ best10,
                         float* __restrict__ out, int N) {
  int n = blockIdx.x * blockDim.x + threadIdx.x;
  if (n >= N) return;
  u32 k = best01[n];
  int idx01 = (int)((~k) & IDX_BITS);
  float sim = __uint_as_float(k & VAL_MASK) - 2.0f;  // undo +2 bias
  int idx10 = (int)((~best10[idx01]) & IDX_BITS);
  float dist = 2.0f - 2.0f * sim;             // squared L2 for unit vectors
  bool ok = (idx10 == n) && (dist <= 0.64f);  // mutual NN + thresh^2
  out[n]     = ok ? (float)idx01 : -1.0f;
  out[N + n] = ok ? 1.5f - sim : 0.0f;        // (dist+1)/2
}

// ---------- launcher ----------

extern "C" void kernel_launch(void* const* d_in, const int* in_sizes, int n_in,
                              void* d_out, int out_size, void* d_ws, size_t ws_size,
                              hipStream_t stream) {
  (void)n_in; (void)out_size;
  const float* d0 = (const float*)d_in[0];  // [256][N]
  const float* d1 = (const float*)d_in[1];  // [256][M]
  const int N = in_sizes[0] / D_DIM;        // 8192
  const int M = in_sizes[1] / D_DIM;        // 8192

  u32* best01 = (u32*)d_ws;                            // N u32
  u32* best10 = best01 + N;                            // M u32
  unsigned short* At  = (unsigned short*)(best10 + M); // [N][256] bf16
  unsigned short* Bt2 = At + (size_t)N * D_DIM;        // [M/32][frag-ordered] bf16
  float* out = (float*)d_out;

  const int nBlocks = (N / 256) * (M / 256);
  const size_t need = (size_t)(N + M) * sizeof(u32) +
                      (size_t)(N + M) * D_DIM * sizeof(unsigned short);

  if (ws_size >= need) {
    hipLaunchKernelGGL(transpose_cast2, dim3((N + M) / 64, 2), dim3(256), 0, stream,
                       d0, d1, At, Bt2, N, M, best01, N + M);
    hipLaunchKernelGGL((gemm_reduce<true>), dim3(nBlocks), dim3(256), 0, stream,
                       d0, At, Bt2, best01, best10, N, M);
  } else {
    // ws too small for At: B-only frag-precast (N=0 -> all blocks do B),
    // inline A cast in the GEMM
    unsigned short* BtF = (unsigned short*)(best10 + M);
    hipLaunchKernelGGL(transpose_cast2, dim3(M / 64, 2), dim3(256), 0, stream,
                       d1, d1, BtF, BtF, 0, M, best01, N + M);
    hipLaunchKernelGGL((gemm_reduce<false>), dim3(nBlocks), dim3(256), 0, stream,
                       d0, BtF, BtF, best01, best10, N, M);
  }
  hipLaunchKernelGGL(finalize, dim3(N / 256), dim3(256), 0, stream, best01, best10, out, N);
}